// Round 3
// baseline (32.709 us; speedup 1.0000x reference)
//
#include <hip/hip_runtime.h>
#include <limits.h>

// HeadTail aggregation with EXACT JAX semantics under x64-disabled:
// the reference's index = ((arange(N,int64)*G)//N).astype(int32) silently
// computes in int32 -> i*G WRAPS (N*G ~ 2e11 >> 2^31). So the real index
// buffer is an unsorted sawtooth in ~[-1074, 1073] incl. NEGATIVES.
// Prior rounds' aborts were OOB writes at out[index[i]*...] with negative g.
//
// JAX semantics emulated:
//  - segment_min/max: out-of-range segment ids DROPPED; empty segments get
//    identity (INT32_MAX for min, INT32_MIN for max).
//  - x[idx] gather: negative idx += N, then CLIP to [0, N-1].
//    => INT_MAX -> x[N-1], INT_MIN -> x[0].
// This is also correct for the "clean" sorted index, so it's robust either way.

__global__ void ht_init_kernel(int* __restrict__ head, int* __restrict__ tail,
                               int G) {
    int i = blockIdx.x * blockDim.x + threadIdx.x;
    int stride = gridDim.x * blockDim.x;
    for (; i < G; i += stride) {
        head[i] = INT_MAX;   // segment_min identity for int32
        tail[i] = INT_MIN;   // segment_max identity for int32
    }
}

// Atomic min/max only at run boundaries (index has ~20-long runs of equal
// values) -> ~2*N/20 atomics total instead of 2N.
__global__ void ht_scan_kernel(const int* __restrict__ index,
                               int* __restrict__ head, int* __restrict__ tail,
                               int N, int G) {
    int i = blockIdx.x * blockDim.x + threadIdx.x;
    int stride = gridDim.x * blockDim.x;
    for (; i < N; i += stride) {
        int g = index[i];
        if (g < 0 || g >= G) continue;   // JAX drops out-of-range segment ids
        bool run_start = (i == 0) || (index[i - 1] != g);
        bool run_end   = (i == N - 1) || (index[i + 1] != g);
        if (run_start) atomicMin(&head[g], i);
        if (run_end)   atomicMax(&tail[g], i);
    }
}

// One float4 per thread; 32 threads per group (16 head half, 16 tail half).
__global__ void ht_gather_kernel(const float4* __restrict__ x4,
                                 const int* __restrict__ head,
                                 const int* __restrict__ tail,
                                 float4* __restrict__ out4,
                                 int G, int N) {
    long long tid = (long long)blockIdx.x * blockDim.x + threadIdx.x;
    long long total = (long long)G * 32;
    if (tid >= total) return;
    int g = (int)(tid >> 5);
    int c = (int)(tid & 31);

    int r = (c < 16) ? head[g] : tail[g];
    // JAX gather index normalization: wrap negatives, then clip.
    if (r < 0) r += N;                 // INT_MIN stays hugely negative
    r = min(max(r, 0), N - 1);         // INT_MAX -> N-1, INT_MIN -> 0
    int cc = c & 15;
    out4[(long long)g * 32 + c] = x4[(long long)r * 16 + cc];
}

extern "C" void kernel_launch(void* const* d_in, const int* in_sizes, int n_in,
                              void* d_out, int out_size, void* d_ws, size_t ws_size,
                              hipStream_t stream) {
    const float* x = (const float*)d_in[0];   // [N, 64] f32
    const int* index = (const int*)d_in[1];   // [N] i32 (garbage sawtooth!)
    const int N = in_sizes[1];
    const int G = out_size / 128;             // out is [G, 128] f32

    int* head = (int*)d_ws;                   // [G]
    int* tail = head + G;                     // [G]  (needs 2*G*4 = 800 KB ws)

    {
        int block = 256;
        int grid = (G + block - 1) / block;   // 391 blocks
        ht_init_kernel<<<grid, block, 0, stream>>>(head, tail, G);
    }
    {
        int block = 256;
        int grid = (N + block - 1) / block;   // 7813 blocks
        ht_scan_kernel<<<grid, block, 0, stream>>>(index, head, tail, N, G);
    }
    {
        long long total = (long long)G * 32;
        int block = 256;
        int grid = (int)((total + block - 1) / block);  // 12500 blocks
        ht_gather_kernel<<<grid, block, 0, stream>>>(
            (const float4*)x, head, tail, (float4*)d_out, G, N);
    }
}

// Round 4
// 28.567 us; speedup vs baseline: 1.1450x; 1.1450x over previous
//
#include <hip/hip_runtime.h>
#include <limits.h>

// HeadTail aggregation, JAX x64-disabled semantics:
// index = ((arange(N,i64)*G)//N).astype(i32) computed in int32 -> WRAPS ->
// unsorted sawtooth in ~[-1074,1073] incl. negatives.
//  - segment_min/max: out-of-range ids dropped; empty segs get identity
//    (INT32_MAX for min, INT32_MIN for max).
//  - x[idx] gather: negative idx += N, then clip to [0,N-1].
//
// Encoding trick (kills the init kernel): ws is one 0xFF memset.
//   head_u[g] = min over unsigned i           (empty -> 0xFFFFFFFF)
//   tail_u[g] = min over unsigned ~i          (empty -> 0xFFFFFFFF)
// Decode: head r = (int)head_u  -> empty = -1 -> +N -> N-1  == JAX INT_MAX clip
//         tail r = (int)~tail_u -> empty =  0          == JAX INT_MIN clip

__global__ void ht_scan_kernel(const int4* __restrict__ idx4,
                               const int* __restrict__ index,
                               unsigned* __restrict__ head_u,
                               unsigned* __restrict__ tail_u,
                               int N, int G) {
    int nv = N >> 2;
    int j = blockIdx.x * blockDim.x + threadIdx.x;
    if (j < nv) {
        int4 v = idx4[j];
        int base = j << 2;
        // Force run_start at i==0 / run_end at i==N-1 by making the sentinel differ.
        int prev = (base == 0) ? (v.x ^ 1) : index[base - 1];
        int next = (base + 4 >= N) ? (v.w ^ 1) : index[base + 4];
        int a[6] = {prev, v.x, v.y, v.z, v.w, next};
        #pragma unroll
        for (int k = 0; k < 4; ++k) {      // fully unrolled -> static indexing
            int g = a[k + 1];
            if (g < 0 || g >= G) continue; // JAX drops out-of-range ids
            if (a[k] != g)     atomicMin(&head_u[g], (unsigned)(base + k));
            if (a[k + 2] != g) atomicMin(&tail_u[g], ~(unsigned)(base + k));
        }
    }
    // Remainder elements (N % 4 != 0), handled by one thread; N=2M -> no-op.
    if (j == 0) {
        for (int i = nv << 2; i < N; ++i) {
            int g = index[i];
            if (g < 0 || g >= G) continue;
            bool rs = (i == 0) || (index[i - 1] != g);
            bool re = (i == N - 1) || (index[i + 1] != g);
            if (rs) atomicMin(&head_u[g], (unsigned)i);
            if (re) atomicMin(&tail_u[g], ~(unsigned)i);
        }
    }
}

// One float4 per thread; 32 threads per group. Writes are contiguous per wave.
__global__ void ht_gather_kernel(const float4* __restrict__ x4,
                                 const unsigned* __restrict__ head_u,
                                 const unsigned* __restrict__ tail_u,
                                 float4* __restrict__ out4,
                                 int G, int N) {
    long long tid = (long long)blockIdx.x * blockDim.x + threadIdx.x;
    long long total = (long long)G * 32;
    if (tid >= total) return;
    int g = (int)(tid >> 5);
    int c = (int)(tid & 31);

    int r = (c < 16) ? (int)head_u[g] : (int)(~tail_u[g]);
    if (r < 0) r += N;                 // JAX negative-index wrap
    r = min(max(r, 0), N - 1);         // JAX clip
    out4[tid] = x4[(long long)r * 16 + (c & 15)];
}

extern "C" void kernel_launch(void* const* d_in, const int* in_sizes, int n_in,
                              void* d_out, int out_size, void* d_ws, size_t ws_size,
                              hipStream_t stream) {
    const float* x = (const float*)d_in[0];   // [N, 64] f32
    const int* index = (const int*)d_in[1];   // [N] i32 (wrapped sawtooth)
    const int N = in_sizes[1];
    const int G = out_size / 128;             // out is [G, 128] f32

    unsigned* head_u = (unsigned*)d_ws;       // [G]
    unsigned* tail_u = head_u + G;            // [G]  (2*G*4 = 800 KB ws)

    // Single fill: 0xFF == identity for both encodings.
    hipMemsetAsync(d_ws, 0xFF, (size_t)2 * G * sizeof(unsigned), stream);

    {
        int nv = N >> 2;
        int block = 256;
        int grid = (nv + block - 1) / block;  // 1954 blocks
        ht_scan_kernel<<<grid, block, 0, stream>>>(
            (const int4*)index, index, head_u, tail_u, N, G);
    }
    {
        long long total = (long long)G * 32;
        int block = 256;
        int grid = (int)((total + block - 1) / block);  // 12500 blocks
        ht_gather_kernel<<<grid, block, 0, stream>>>(
            (const float4*)x, head_u, tail_u, (float4*)d_out, G, N);
    }
}